// Round 2
// baseline (1225.888 us; speedup 1.0000x reference)
//
#include <hip/hip_runtime.h>
#include <hip/hip_bf16.h>
#include <cmath>

#define NROWS 100000
#define DIM   1024
#define LH    128
#define NSEG  16
#define EPSF  1e-16f
#define CHUNK 128

#define OUT_OFF   0
#define SCORE_OFF (NSEG * DIM)            /* 16384   */
#define SM_OFF    (SCORE_OFF + NROWS)     /* 116384  */
#define FEAT_OFF  (SM_OFF + NROWS)        /* 216384  */

typedef __attribute__((ext_vector_type(4))) float floatx4;
typedef __attribute__((ext_vector_type(8))) short shortx8;

__device__ __forceinline__ unsigned short f2bf(float x) {
    unsigned u = __float_as_uint(x);
    u += 0x7FFFu + ((u >> 16) & 1u);          // round-to-nearest-even
    return (unsigned short)(u >> 16);
}
__device__ __forceinline__ unsigned enc_f32(float f) {   // monotone float->uint
    unsigned u = __float_as_uint(f);
    return (u & 0x80000000u) ? ~u : (u | 0x80000000u);
}
__device__ __forceinline__ float dec_f32(unsigned e) {
    unsigned u = (e & 0x80000000u) ? (e ^ 0x80000000u) : ~e;
    return __uint_as_float(u);
}

// ---------------------------------------------------------------- init -----
// Convert Wa,Wb (fp32) -> combined bf16 W[256][1024] in ws; zero segmax,
// denom, out-accumulator; binary-search sorted batch -> segstart[17].
// Runs every launch (ws and d_out are re-poisoned before each timed call).
__global__ void init_kernel(const float* __restrict__ Wa,
                            const float* __restrict__ Wb,
                            const int* __restrict__ batch,
                            unsigned short* __restrict__ wbf,
                            unsigned* __restrict__ segmax,
                            float* __restrict__ denom,
                            int* __restrict__ segstart,
                            float* __restrict__ out) {
    int idx = blockIdx.x * 256 + threadIdx.x;      // grid covers 262144
    if (idx < LH * DIM)
        wbf[idx] = f2bf(Wa[idx]);
    else if (idx < 2 * LH * DIM)
        wbf[idx] = f2bf(Wb[idx - LH * DIM]);
    if (idx < NSEG * DIM) out[OUT_OFF + idx] = 0.f;
    if (idx < NSEG) { segmax[idx] = 0u; denom[idx] = 0.f; }
    if (blockIdx.x == 0 && threadIdx.x <= NSEG) {
        // first index with batch[i] >= b  (batch sorted ascending)
        const int b = threadIdx.x;
        int lo = 0, hi = NROWS;
        while (lo < hi) {
            const int mid = (lo + hi) >> 1;
            if (batch[mid] < b) lo = mid + 1; else hi = mid;
        }
        segstart[b] = lo;
    }
}

// --------------------------------------------------------------- score -----
// Barrier-free MFMA. Block = 4 waves; wave owns 16 rows (block = 64 rows).
// Per 32-wide k-step each lane loads its A-fragment directly from feature
// (fp32 -> bf16 in-register) and 16 B-fragments from the L2-resident bf16
// weight copy. No LDS staging, no K-loop barriers.
__launch_bounds__(256)
__global__ void score_kernel(const float* __restrict__ feature,
                             const int* __restrict__ batch,
                             const unsigned short* __restrict__ wbf,
                             const float* __restrict__ ba,
                             const float* __restrict__ bb,
                             const float* __restrict__ wc,
                             const float* __restrict__ bc,
                             float* __restrict__ outp,
                             unsigned* __restrict__ segmax) {
    __shared__ float sBias[3 * LH];
    __shared__ float sScore[64];
    __shared__ int   sBatch[64];
    __shared__ unsigned sMax[NSEG];

    const int tid  = threadIdx.x;
    const int wave = tid >> 6;
    const int lane = tid & 63;
    const int q    = lane >> 4;    // quad: k-group (A/B), row-group (C)
    const int c    = lane & 15;    // m (A row) / n (B row) within 16-tile
    const int row0 = blockIdx.x * 64;

    if (tid < LH) {
        sBias[tid]          = ba[tid];
        sBias[LH + tid]     = bb[tid];
        sBias[2 * LH + tid] = wc[tid];
    }
    if (tid < NSEG) sMax[tid] = 0u;
    if (tid < 64)   sBatch[tid] = -1;

    const int rowA  = row0 + wave * 16 + c;
    const int rowAs = rowA < NROWS ? rowA : (NROWS - 1);   // clamp; guarded later
    const float* __restrict__ arow = feature + (size_t)rowAs * DIM + q * 8;
    const unsigned short* __restrict__ wbase = wbf + (size_t)c * DIM + q * 8;

    floatx4 acc[16];
#pragma unroll
    for (int t = 0; t < 16; ++t)
#pragma unroll
        for (int i = 0; i < 4; ++i) acc[t][i] = 0.f;

#pragma unroll 2
    for (int k0 = 0; k0 < DIM; k0 += 32) {
        const floatx4 a0 = *(const floatx4*)(arow + k0);
        const floatx4 a1 = *(const floatx4*)(arow + k0 + 4);
        shortx8 af;
        af[0] = (short)f2bf(a0[0]); af[1] = (short)f2bf(a0[1]);
        af[2] = (short)f2bf(a0[2]); af[3] = (short)f2bf(a0[3]);
        af[4] = (short)f2bf(a1[0]); af[5] = (short)f2bf(a1[1]);
        af[6] = (short)f2bf(a1[2]); af[7] = (short)f2bf(a1[3]);
#pragma unroll
        for (int t = 0; t < 16; ++t) {
            const shortx8 bf = *(const shortx8*)(wbase + (size_t)t * 16 * DIM + k0);
            acc[t] = __builtin_amdgcn_mfma_f32_16x16x32_bf16(af, bf, acc[t], 0, 0, 0);
        }
    }

    // ---- epilogue: bias + sigmoid*tanh gate + Wc dot ----
    float p4[4] = {0.f, 0.f, 0.f, 0.f};
#pragma unroll
    for (int t = 0; t < 8; ++t) {
        const int col = t * 16 + c;
        const float bav = sBias[col];
        const float bbv = sBias[LH + col];
        const float wcv = sBias[2 * LH + col];
#pragma unroll
        for (int i = 0; i < 4; ++i) {
            float u = acc[t][i] + bav;         // a-logit
            float v = acc[t + 8][i] + bbv;     // b-logit
            float sg = 1.f / (1.f + __expf(-u));
            float th = tanhf(v);
            p4[i] += sg * th * wcv;
        }
    }
#pragma unroll
    for (int i = 0; i < 4; ++i) {              // reduce over 16 cols
        p4[i] += __shfl_xor(p4[i], 1, 16);
        p4[i] += __shfl_xor(p4[i], 2, 16);
        p4[i] += __shfl_xor(p4[i], 4, 16);
        p4[i] += __shfl_xor(p4[i], 8, 16);
    }

    __syncthreads();                           // sBatch init + LDS reads safe

    const float bcv = bc[0];
    if (c == 0) {
#pragma unroll
        for (int i = 0; i < 4; ++i) {
            const int r    = wave * 16 + q * 4 + i;
            const int grow = row0 + r;
            if (grow < NROWS) {
                const float s = p4[i] + bcv;
                outp[SCORE_OFF + grow] = s;
                sScore[r] = s;
                sBatch[r] = batch[grow];
            }
        }
    }
    __syncthreads();
    if (tid < 64 && sBatch[tid] >= 0)
        atomicMax(&sMax[sBatch[tid]], enc_f32(sScore[tid]));
    __syncthreads();
    if (tid < NSEG && sMax[tid] != 0u)
        atomicMax(&segmax[tid], sMax[tid]);
}

// ----------------------------------------------------------------- exp -----
__global__ void exp_kernel(const float* __restrict__ score,
                           const int* __restrict__ batch,
                           const unsigned* __restrict__ segmax,
                           float* __restrict__ evals,
                           float* __restrict__ denom) {
    __shared__ float sden[NSEG];
    const int tid = threadIdx.x;
    const int idx = blockIdx.x * 256 + tid;
    if (tid < NSEG) sden[tid] = 0.f;
    __syncthreads();
    if (idx < NROWS) {
        const int b = batch[idx];
        const float m = dec_f32(segmax[b]);
        const float e = expf(score[idx] - m);
        evals[idx] = e;
        atomicAdd(&sden[b], e);
    }
    __syncthreads();
    if (tid < NSEG && sden[tid] != 0.f) atomicAdd(&denom[tid], sden[tid]);
}

// ---------------------------------------------------------------- norm -----
// In-place e -> softmax  (score_softmax output).
__global__ void norm_kernel(const int* __restrict__ batch,
                            const float* __restrict__ denom,
                            float* __restrict__ evals) {
    const int idx = blockIdx.x * 256 + threadIdx.x;
    if (idx < NROWS)
        evals[idx] = evals[idx] / (denom[batch[idx]] + EPSF);
}

// ---------------------------------------------------------------- wsum -----
// Grid (chunk, segment): block rows are single-segment by construction.
// Branch-free inner loop: load feature, echo it, FMA with softmax weight.
// One atomicAdd set per thread at the end.
__launch_bounds__(256)
__global__ void wsum_kernel(const float* __restrict__ feature,
                            const int* __restrict__ segstart,
                            const float* __restrict__ sm,   // normalized softmax
                            float* __restrict__ outp) {
    const int s   = blockIdx.y;
    const int beg = segstart[s];
    const int end = segstart[s + 1];
    const int r0  = beg + blockIdx.x * CHUNK;
    if (r0 >= end) return;
    const int nr = min(CHUNK, end - r0);

    __shared__ float sw[CHUNK];
    const int tid = threadIdx.x;
    if (tid < CHUNK) sw[tid] = (tid < nr) ? sm[r0 + tid] : 0.f;
    __syncthreads();

    const int cc = tid * 4;
    floatx4 acc; acc[0] = acc[1] = acc[2] = acc[3] = 0.f;
#pragma unroll 4
    for (int r = 0; r < nr; ++r) {
        const float* __restrict__ src = feature + (size_t)(r0 + r) * DIM + cc;
        const floatx4 f = *(const floatx4*)src;
        *(floatx4*)(outp + FEAT_OFF + (size_t)(r0 + r) * DIM + cc) = f;  // echo
        const float w = sw[r];
        acc[0] += w * f[0];
        acc[1] += w * f[1];
        acc[2] += w * f[2];
        acc[3] += w * f[3];
    }
#pragma unroll
    for (int j = 0; j < 4; ++j)
        atomicAdd(&outp[OUT_OFF + s * DIM + cc + j], acc[j]);
}

// -------------------------------------------------------------- launch -----
extern "C" void kernel_launch(void* const* d_in, const int* in_sizes, int n_in,
                              void* d_out, int out_size, void* d_ws, size_t ws_size,
                              hipStream_t stream) {
    const float* feature = (const float*)d_in[0];
    const int*   batch   = (const int*)d_in[1];
    const float* Wa      = (const float*)d_in[2];
    const float* ba      = (const float*)d_in[3];
    const float* Wb      = (const float*)d_in[4];
    const float* bb      = (const float*)d_in[5];
    const float* Wc      = (const float*)d_in[6];
    const float* bc      = (const float*)d_in[7];
    float* out = (float*)d_out;

    char* ws = (char*)d_ws;
    unsigned short* wbf    = (unsigned short*)ws;                 // 512 KB
    unsigned*       segmax = (unsigned*)(ws + 2 * LH * DIM * 2);  // 16 u32
    float*          denom  = (float*)(ws + 2 * LH * DIM * 2 + 64);
    int*            segst  = (int*)(ws + 2 * LH * DIM * 2 + 128); // 17 i32

    init_kernel<<<(2 * LH * DIM) / 256, 256, 0, stream>>>(
        Wa, Wb, batch, wbf, segmax, denom, segst, out);
    score_kernel<<<(NROWS + 63) / 64, 256, 0, stream>>>(
        feature, batch, wbf, ba, bb, Wc, bc, out, segmax);
    exp_kernel<<<(NROWS + 255) / 256, 256, 0, stream>>>(
        out + SCORE_OFF, batch, segmax, out + SM_OFF, denom);
    norm_kernel<<<(NROWS + 255) / 256, 256, 0, stream>>>(
        batch, denom, out + SM_OFF);
    dim3 wgrid((NROWS + CHUNK - 1) / CHUNK, NSEG);
    wsum_kernel<<<wgrid, 256, 0, stream>>>(feature, segst, out + SM_OFF, out);
}